// Round 2
// baseline (239.889 us; speedup 1.0000x reference)
//
#include <hip/hip_runtime.h>

typedef unsigned short ushort_t;
typedef unsigned int u32;
typedef _Float16 f16;
typedef f16 f16x8 __attribute__((ext_vector_type(8)));
typedef f16 f16x2 __attribute__((ext_vector_type(2)));
typedef ushort_t u16x8 __attribute__((ext_vector_type(8)));
typedef float f32x4 __attribute__((ext_vector_type(4)));
typedef float f32x16 __attribute__((ext_vector_type(16)));

#define C_DIM 256
#define HW 4096
#define CHW (C_DIM*HW)
#define L2E 1.4426950408889634f

// Device-global scratch. Internal pipeline f16.
__device__ __align__(16) f16 g_xbT[4 * CHW];
__device__ __align__(16) f16 g_q[4 * CHW];
__device__ __align__(16) f16 g_k[4 * CHW];
__device__ __align__(16) f16 g_v[4 * CHW];
__device__ __align__(16) f16 g_opart[16 * CHW];   // [slot=jq*4+n][c][i] normalized O^T
__device__ __align__(16) float g_ml[16 * 2 * HW]; // [slot][{m,l}][i]

__device__ __forceinline__ float bf2f(ushort_t h) {
    union { u32 u; float f; } v; v.u = ((u32)h) << 16; return v.f;
}
__device__ __forceinline__ ushort_t f2bf(float f) {
    union { float f; u32 u; } v; v.f = f;
    u32 r = v.u + 0x7FFF + ((v.u >> 16) & 1);
    return (ushort_t)(r >> 16);
}
__device__ __forceinline__ float fin0(float v) {
    return (v > -1e30f && v < 1e30f) ? v : 0.f;
}
__device__ __forceinline__ f16 sf16(float v) {
    return (f16)((v > -1e4f && v < 1e4f) ? v : 0.f);
}
__device__ __forceinline__ void gl2lds16(const f16* g, f16* l) {
    __builtin_amdgcn_global_load_lds(
        (const __attribute__((address_space(1))) u32*)g,
        (__attribute__((address_space(3))) u32*)l, 16, 0, 0);
}
// Local dtype probe: read 64 halves as bf16; f32-misread low-halves decode huge.
__device__ __forceinline__ int probe_mode(const void* p) {
    int lane = threadIdx.x & 63;
    float v = fabsf(bf2f(((const ushort_t*)p)[lane]));
    v = (v < 1e6f) ? v : 1e6f;
#pragma unroll
    for (int d = 1; d < 64; d <<= 1) v += __shfl_xor(v, d, 64);
    return (v * (1.f / 64.f) > 100.f) ? 1 : 0;
}

__global__ void k_sentinel(ushort_t* out, int n) {
    int i = blockIdx.x * 256 + threadIdx.x;
    if (i < n) out[i] = f2bf(777.f);
}

// ---------------- kernel 1: x (N,C,HW) -> g_xbT f16 (N,HW,C) ----------------
__global__ __launch_bounds__(256) void k_transpose(const void* __restrict__ xv) {
    __shared__ f16 t[64][66];
    int mode = probe_mode(xv);
    int n = blockIdx.z, c0 = blockIdx.y * 64, l0 = blockIdx.x * 64;
    int tid = threadIdx.x;
    f16* ob = g_xbT + n * CHW;
    int lq = (tid & 15) * 4;
    int cl = tid >> 4;
    if (mode == 0) {
        const ushort_t* xb = (const ushort_t*)xv + n * CHW;
#pragma unroll
        for (int p = 0; p < 4; ++p) {
            int c = cl + 16 * p;
            ushort4 v = *(const ushort4*)(xb + (c0 + c) * HW + l0 + lq);
            t[lq + 0][c] = sf16(bf2f(v.x));
            t[lq + 1][c] = sf16(bf2f(v.y));
            t[lq + 2][c] = sf16(bf2f(v.z));
            t[lq + 3][c] = sf16(bf2f(v.w));
        }
    } else {
        const float* xb = (const float*)xv + n * CHW;
#pragma unroll
        for (int p = 0; p < 4; ++p) {
            int c = cl + 16 * p;
            float4 v = *(const float4*)(xb + (c0 + c) * HW + l0 + lq);
            t[lq + 0][c] = sf16(v.x);
            t[lq + 1][c] = sf16(v.y);
            t[lq + 2][c] = sf16(v.z);
            t[lq + 3][c] = sf16(v.w);
        }
    }
    __syncthreads();
    int c2 = (tid & 31) * 2;
    int lr = tid >> 5;
#pragma unroll
    for (int p = 0; p < 8; ++p) {
        int l = lr + 8 * p;
        u32 pair = *(const u32*)&t[l][c2];
        *(u32*)(ob + (l0 + l) * C_DIM + c0 + c2) = pair;
    }
}

// ---------------- kernel 2: projections (f16 MFMA) ----------------
__global__ __launch_bounds__(256) void k_proj(
    const void* __restrict__ Wq, const void* __restrict__ bq,
    const void* __restrict__ Wk, const void* __restrict__ bk,
    const void* __restrict__ Wv, const void* __restrict__ bv)
{
    __shared__ __align__(16) f16 lds_x[128 * 64];
    __shared__ __align__(16) f16 lds_w[128 * 64];
    int l0 = blockIdx.x * 128;
    int og0 = blockIdx.y * 128;
    int n = blockIdx.z;
    int mat = og0 >> 8;       // 0=q,1=k,2=v
    int om0 = og0 & 255;
    const void* W = (mat == 0) ? Wq : (mat == 1) ? Wk : Wv;
    const void* bias = (mat == 0) ? bq : (mat == 1) ? bk : bv;
    int mode = probe_mode(W);
    int tid = threadIdx.x, w = tid >> 6, lane = tid & 63;
    int quad = lane >> 4, l16 = lane & 15;
    const f16* xb = g_xbT + n * CHW;

    f32x4 acc[2][8];
#pragma unroll
    for (int a = 0; a < 2; a++)
#pragma unroll
        for (int b = 0; b < 8; b++) acc[a][b] = f32x4{0.f, 0.f, 0.f, 0.f};

    for (int ch = 0; ch < 4; ++ch) {
        int cc0 = ch * 64;
        f16x8 xs[4], wsr[4];
#pragma unroll
        for (int ti = 0; ti < 4; ++ti) {
            int s = (w * 4 + ti) * 64 + lane;
            int row = s >> 3, gp = s & 7;
            xs[ti] = *(const f16x8*)(xb + (l0 + row) * C_DIM + cc0 + gp * 8);
            f16x8 h;
            if (mode == 0) {
                u16x8 wv = *(const u16x8*)((const ushort_t*)W + (om0 + row) * C_DIM + cc0 + gp * 8);
#pragma unroll
                for (int e = 0; e < 8; e++) h[e] = sf16(bf2f(wv[e]));
            } else {
                const float* wf = (const float*)W + (om0 + row) * C_DIM + cc0 + gp * 8;
#pragma unroll
                for (int e = 0; e < 8; e++) h[e] = sf16(wf[e]);
            }
            wsr[ti] = h;
        }
        __syncthreads();
#pragma unroll
        for (int ti = 0; ti < 4; ++ti) {
            int s = (w * 4 + ti) * 64 + lane;
            int row = s >> 3, gp = s & 7;
            int pos = gp ^ (row & 7);
            *(f16x8*)(lds_x + (row * 8 + pos) * 8) = xs[ti];
            *(f16x8*)(lds_w + (row * 8 + pos) * 8) = wsr[ti];
        }
        __syncthreads();
#pragma unroll
        for (int ks = 0; ks < 2; ++ks) {
            f16x8 af[2];
#pragma unroll
            for (int mt = 0; mt < 2; ++mt) {
                int row = w * 32 + mt * 16 + l16;
                int g = ks * 4 + quad;
                int pos = g ^ (row & 7);
                af[mt] = *(const f16x8*)(lds_x + (row * 8 + pos) * 8);
            }
#pragma unroll
            for (int nt = 0; nt < 8; ++nt) {
                int rowo = nt * 16 + l16;
                int g = ks * 4 + quad;
                int pos = g ^ (rowo & 7);
                f16x8 bfv = *(const f16x8*)(lds_w + (rowo * 8 + pos) * 8);
                if (mat < 2) {
                    acc[0][nt] = __builtin_amdgcn_mfma_f32_16x16x32_f16(af[0], bfv, acc[0][nt], 0, 0, 0);
                    acc[1][nt] = __builtin_amdgcn_mfma_f32_16x16x32_f16(af[1], bfv, acc[1][nt], 0, 0, 0);
                } else {
                    acc[0][nt] = __builtin_amdgcn_mfma_f32_16x16x32_f16(bfv, af[0], acc[0][nt], 0, 0, 0);
                    acc[1][nt] = __builtin_amdgcn_mfma_f32_16x16x32_f16(bfv, af[1], acc[1][nt], 0, 0, 0);
                }
            }
        }
        __syncthreads();
    }

    auto loadb = [&](int i) -> float {
        return mode ? ((const float*)bias)[i] : bf2f(((const ushort_t*)bias)[i]);
    };
    if (mat < 2) {
        f16* T = ((mat == 0) ? g_q : g_k) + n * CHW;
        float bvv[8];
#pragma unroll
        for (int nt = 0; nt < 8; nt++) bvv[nt] = loadb(om0 + nt * 16 + l16);
#pragma unroll
        for (int mt = 0; mt < 2; mt++)
#pragma unroll
            for (int nt = 0; nt < 8; nt++)
#pragma unroll
                for (int r = 0; r < 4; r++) {
                    int l = l0 + w * 32 + mt * 16 + quad * 4 + r;
                    int o = om0 + nt * 16 + l16;
                    T[l * C_DIM + o] = sf16(acc[mt][nt][r] + bvv[nt]);
                }
    } else {
        f16* T = g_v + n * CHW;
#pragma unroll
        for (int mt = 0; mt < 2; mt++)
#pragma unroll
            for (int nt = 0; nt < 8; nt++)
#pragma unroll
                for (int r = 0; r < 4; r++) {
                    int o = om0 + nt * 16 + quad * 4 + r;
                    int l = l0 + w * 32 + mt * 16 + l16;
                    T[o * HW + l] = sf16(acc[mt][nt][r] + loadb(o));
                }
    }
}

// ---------------- kernel 3: flash attention, 32x32x16 MFMA ----------------
// Per wave: one 32x32 S^T tile (A=K,B=Q so row j is in-lane), in-register
// softmax + P^T fragment build (cvt + shfl_xor(32), no LDS round-trip).
// PV deferred one iteration: PV(it-1) MFMAs overlap softmax(it) VALU.
// LDS: K double-buffered [cg][j][8] (16KB/slot), V triple-buffered [jg][c][8]
// (16KB/slot) = 80KB total -> 2 blocks/CU. All ds_read_b128 are contiguous
// 512B per 32-lane half -> zero bank conflicts; DMA dests linear (no swizzle).
__device__ __forceinline__ f16x8 pack_pfrag(const float* p, int h) {
    // p[r] holds P^T[j = (r&3)+8*(r>>2)+4*h][i = lane&31] for one 16-j chunk.
    // Build B-operand frag: lane needs j = h*8+e (e=0..7) of this chunk.
    union PK { u32 u; f16x2 h2; } t0, t1, t2, t3;
    t0.h2 = f16x2{(f16)p[0], (f16)p[1]};
    t1.h2 = f16x2{(f16)p[2], (f16)p[3]};
    t2.h2 = f16x2{(f16)p[4], (f16)p[5]};
    t3.h2 = f16x2{(f16)p[6], (f16)p[7]};
    u32 sa = __shfl_xor(t0.u, 32, 64);
    u32 sb = __shfl_xor(t1.u, 32, 64);
    u32 sc = __shfl_xor(t2.u, 32, 64);
    u32 sd = __shfl_xor(t3.u, 32, 64);
    union RW { u32 w[4]; f16x8 v; } r;
    r.w[0] = h ? sc : t0.u;   // k{0,1}: h0 j{0,1}=own t0 ; h1 j{8,9}=partner t2
    r.w[1] = h ? sd : t1.u;   // k{2,3}
    r.w[2] = h ? t2.u : sa;   // k{4,5}: h0 j{4,5}=partner t0 ; h1 j{12,13}=own t2
    r.w[3] = h ? t3.u : sb;   // k{6,7}
    return r.v;
}

__global__ __launch_bounds__(256, 2) void k_attn() {
    __shared__ __align__(16) f16 smem[40960];   // 80 KB
    f16* kbuf = smem;            // 2 slots x 8192 halves, granule g=cg*32+j: K[j][cg*8..+8]
    f16* vbuf = smem + 16384;    // 3 slots x 8192 halves, granule g=jg*256+c: V[c][jg*8..+8]

    int bid = blockIdx.x;
    int x8 = bid & 7;
    int n = x8 >> 1, jhi = x8 & 1;
    int rest = bid >> 3;
    int jlo = rest & 1;
    int i0 = (rest >> 1) * 128;
    int jq = jhi * 2 + jlo;
    int tid = threadIdx.x, w = tid >> 6, lane = tid & 63;
    int j5 = lane & 31, h = lane >> 5;

    const f16* Qb = g_q + n * CHW;
    const f16* Kb = g_k + n * CHW;
    const f16* Vb = g_v + n * CHW;

    // ---- Q fragments in registers (B operand: n=i=lane&31, k=h*8+e) ----
    f16x8 qf[16];
    {
        const f16* qrow = Qb + (i0 + w * 32 + j5) * C_DIM + h * 8;
#pragma unroll
        for (int ck = 0; ck < 16; ++ck)
            qf[ck] = *(const f16x8*)(qrow + ck * 16);
    }

    // per-lane LDS read offsets (halves)
    int k_lane = h * 256 + j5 * 8;    // + ck*512          (cg = ck*2 + h, j = j5)
    int v_lane = h * 2048 + j5 * 8;   // + js*4096 + ct*256 (jg = js*2 + h, c = ct*32+j5)

    // staging source pointers (per-lane), advance per iter
    const f16* ksrc = Kb + (jq * 1024 + j5) * C_DIM + (w * 2 + h) * 8;
    const f16* vsrc = Vb + tid * HW + jq * 1024;
    int dst_w = w * 512;              // wave-uniform LDS dest offset (halves)

    f32x16 o_acc[8];
#pragma unroll
    for (int ct = 0; ct < 8; ++ct)
#pragma unroll
        for (int r = 0; r < 16; ++r) o_acc[ct][r] = 0.f;

    float m_ = -1e30f, l_ = 0.f, al_prev = 1.f;
    f16x8 pf0 = {}, pf1 = {};

    // prologue: stage K(0)->kslot0, V(0)->vslot0
#pragma unroll
    for (int s = 0; s < 4; ++s) gl2lds16(ksrc + s * 64, kbuf + s * 2048 + dst_w);
    ksrc += 32 * C_DIM;
#pragma unroll
    for (int s = 0; s < 4; ++s) gl2lds16(vsrc + s * 8, vbuf + s * 2048 + dst_w);
    vsrc += 32;
    __syncthreads();

    int vs_stage = 1, vs_pv = 2;      // at iter it: stage=(it+1)%3, pv=(it-1)%3
    for (int it = 0; it < 32; ++it) {
        int kb_cur = it & 1;
        if (it < 31) {
#pragma unroll
            for (int s = 0; s < 4; ++s)
                gl2lds16(ksrc + s * 64, kbuf + (kb_cur ^ 1) * 8192 + s * 2048 + dst_w);
            ksrc += 32 * C_DIM;
#pragma unroll
            for (int s = 0; s < 4; ++s)
                gl2lds16(vsrc + s * 8, vbuf + vs_stage * 8192 + s * 2048 + dst_w);
            vsrc += 32;
        }

        // ---- S^T(it) = K Q^T : one 32x32 tile per wave ----
        const f16* kb = kbuf + kb_cur * 8192 + k_lane;
        f32x16 st;
#pragma unroll
        for (int r = 0; r < 16; ++r) st[r] = 0.f;
        __builtin_amdgcn_s_setprio(1);
#pragma unroll
        for (int ck = 0; ck < 16; ++ck) {
            f16x8 kf = *(const f16x8*)(kb + ck * 512);
            st = __builtin_amdgcn_mfma_f32_32x32x16_f16(kf, qf[ck], st, 0, 0, 0);
        }

        // ---- deferred PV: O^T += V(it-1) P^T(it-1) (independent of softmax(it)) ----
        if (it > 0) {
            if (__any(al_prev < 1.f)) {
#pragma unroll
                for (int ct = 0; ct < 8; ++ct)
#pragma unroll
                    for (int r = 0; r < 16; ++r) o_acc[ct][r] *= al_prev;
            }
            const f16* vb = vbuf + vs_pv * 8192 + v_lane;
#pragma unroll
            for (int ct = 0; ct < 8; ++ct) {
                f16x8 v0 = *(const f16x8*)(vb + ct * 256);
                f16x8 v1 = *(const f16x8*)(vb + 4096 + ct * 256);
                o_acc[ct] = __builtin_amdgcn_mfma_f32_32x32x16_f16(v0, pf0, o_acc[ct], 0, 0, 0);
                o_acc[ct] = __builtin_amdgcn_mfma_f32_32x32x16_f16(v1, pf1, o_acc[ct], 0, 0, 0);
            }
        }
        __builtin_amdgcn_s_setprio(0);

        // ---- online softmax over j (rows of S^T), per i = lane&31 ----
        float mx0 = fmaxf(fmaxf(st[0], st[1]), fmaxf(st[2], st[3]));
        float mx1 = fmaxf(fmaxf(st[4], st[5]), fmaxf(st[6], st[7]));
        float mx2 = fmaxf(fmaxf(st[8], st[9]), fmaxf(st[10], st[11]));
        float mx3 = fmaxf(fmaxf(st[12], st[13]), fmaxf(st[14], st[15]));
        float smax = fmaxf(fmaxf(mx0, mx1), fmaxf(mx2, mx3));
        smax = fmaxf(smax, __shfl_xor(smax, 32, 64));
        float mq = __builtin_ceilf(smax * 0.125f) * 8.f;   // quantized max
        float mn = fmaxf(m_, mq);
        float al = __builtin_amdgcn_exp2f((m_ - mn) * L2E);
        float nl = -mn * L2E;
        float p[16];
#pragma unroll
        for (int r = 0; r < 16; ++r)
            p[r] = __builtin_amdgcn_exp2f(st[r] * L2E + nl);
        float a0 = (p[0] + p[1]) + (p[2] + p[3]);
        float a1 = (p[4] + p[5]) + (p[6] + p[7]);
        float a2 = (p[8] + p[9]) + (p[10] + p[11]);
        float a3 = (p[12] + p[13]) + (p[14] + p[15]);
        float rs = (a0 + a1) + (a2 + a3);
        rs += __shfl_xor(rs, 32, 64);
        m_ = mn;
        l_ = l_ * al + rs;
        al_prev = al;
        pf0 = pack_pfrag(p, h);
        pf1 = pack_pfrag(p + 8, h);

        __syncthreads();   // staged(it+1) drained; all buffer reads of (it) done
        vs_pv = (vs_pv == 2) ? 0 : vs_pv + 1;
        vs_stage = (vs_stage == 2) ? 0 : vs_stage + 1;
    }

    // ---- final PV(31) ----
    {
        if (__any(al_prev < 1.f)) {
#pragma unroll
            for (int ct = 0; ct < 8; ++ct)
#pragma unroll
                for (int r = 0; r < 16; ++r) o_acc[ct][r] *= al_prev;
        }
        const f16* vb = vbuf + vs_pv * 8192 + v_lane;
#pragma unroll
        for (int ct = 0; ct < 8; ++ct) {
            f16x8 v0 = *(const f16x8*)(vb + ct * 256);
            f16x8 v1 = *(const f16x8*)(vb + 4096 + ct * 256);
            o_acc[ct] = __builtin_amdgcn_mfma_f32_32x32x16_f16(v0, pf0, o_acc[ct], 0, 0, 0);
            o_acc[ct] = __builtin_amdgcn_mfma_f32_32x32x16_f16(v1, pf1, o_acc[ct], 0, 0, 0);
        }
    }

    // ---- write partials ----
    int slot = jq * 4 + n;
    int i_out = i0 + w * 32 + j5;
    if (h == 0) {
        g_ml[(slot * 2 + 0) * HW + i_out] = m_;
        g_ml[(slot * 2 + 1) * HW + i_out] = l_;
    }
    float inv = (l_ > 1e-30f) ? 1.f / l_ : 0.f;
    f16* ob = g_opart + slot * CHW + i_out;
#pragma unroll
    for (int ct = 0; ct < 8; ++ct) {
        int cbase = ct * 32 + 4 * h;
#pragma unroll
        for (int r = 0; r < 16; ++r) {
            int c = cbase + (r & 3) + 8 * (r >> 2);
            ob[c * HW] = (f16)(o_acc[ct][r] * inv);
        }
    }
}

// ---------------- kernel 4: merge 4 j-quarters + residual + store (8-wide) ----------------
__global__ __launch_bounds__(256) void k_combine(
    const void* __restrict__ xv, const void* __restrict__ gv, void* __restrict__ outv)
{
    int mode = probe_mode(xv);
    float gam = fin0(mode ? ((const float*)gv)[0] : bf2f(((const ushort_t*)gv)[0]));
    int n = blockIdx.y;
    int off = blockIdx.x * 2048 + threadIdx.x * 8;   // 8 consecutive i, same c
    int i = off & (HW - 1);

    u16x8 op[4];
    float ms[4][8], ls[4][8];
#pragma unroll
    for (int s = 0; s < 4; ++s) {
        int slot = s * 4 + n;
        op[s] = *(const u16x8*)((const ushort_t*)g_opart + slot * CHW + off);
        float4 mA = *(const float4*)&g_ml[(slot * 2 + 0) * HW + i];
        float4 mB = *(const float4*)&g_ml[(slot * 2 + 0) * HW + i + 4];
        float4 lA = *(const float4*)&g_ml[(slot * 2 + 1) * HW + i];
        float4 lB = *(const float4*)&g_ml[(slot * 2 + 1) * HW + i + 4];
        ms[s][0]=mA.x; ms[s][1]=mA.y; ms[s][2]=mA.z; ms[s][3]=mA.w;
        ms[s][4]=mB.x; ms[s][5]=mB.y; ms[s][6]=mB.z; ms[s][7]=mB.w;
        ls[s][0]=lA.x; ls[s][1]=lA.y; ls[s][2]=lA.z; ls[s][3]=lA.w;
        ls[s][4]=lB.x; ls[s][5]=lB.y; ls[s][6]=lB.z; ls[s][7]=lB.w;
    }

    float o[8];
#pragma unroll
    for (int e = 0; e < 8; ++e) {
        float m = fmaxf(fmaxf(ms[0][e], ms[1][e]), fmaxf(ms[2][e], ms[3][e]));
        float num = 0.f, den = 0.f;
#pragma unroll
        for (int s = 0; s < 4; ++s) {
            float wgt = __builtin_amdgcn_exp2f((ms[s][e] - m) * L2E) * ls[s][e];
            union { ushort_t u; f16 h; } cv; cv.u = (ushort_t)op[s][e];
            num += wgt * (float)cv.h;
            den += wgt;
        }
        o[e] = (den > 1e-30f) ? num / den : 0.f;
    }

    if (mode == 0) {
        u16x8 xp = *(const u16x8*)((const ushort_t*)xv + n * CHW + off);
        u16x8 res;
#pragma unroll
        for (int e = 0; e < 8; ++e)
            res[e] = f2bf(fin0(bf2f((ushort_t)xp[e]) + gam * o[e]));
        *(u16x8*)((ushort_t*)outv + n * CHW + off) = res;
    } else {
        const float* xb = (const float*)xv + n * CHW + off;
        float* outb = (float*)outv + n * CHW + off;
        float4 xA = *(const float4*)xb;
        float4 xB = *(const float4*)(xb + 4);
        float4 rA, rB;
        rA.x = fin0(xA.x + gam * o[0]); rA.y = fin0(xA.y + gam * o[1]);
        rA.z = fin0(xA.z + gam * o[2]); rA.w = fin0(xA.w + gam * o[3]);
        rB.x = fin0(xB.x + gam * o[4]); rB.y = fin0(xB.y + gam * o[5]);
        rB.z = fin0(xB.z + gam * o[6]); rB.w = fin0(xB.w + gam * o[7]);
        *(float4*)outb = rA;
        *(float4*)(outb + 4) = rB;
    }
}

extern "C" void kernel_launch(void* const* d_in, const int* in_sizes, int n_in,
                              void* d_out, int out_size, void* d_ws, size_t ws_size,
                              hipStream_t stream) {
    (void)d_ws; (void)ws_size;
    bool ok = (n_in == 8) &&
              in_sizes[0] == 4 * CHW &&
              in_sizes[1] == C_DIM * C_DIM && in_sizes[2] == C_DIM &&
              in_sizes[3] == C_DIM * C_DIM && in_sizes[4] == C_DIM &&
              in_sizes[5] == C_DIM * C_DIM && in_sizes[6] == C_DIM &&
              in_sizes[7] == 1 && out_size == 4 * CHW;
    if (!ok) {
        hipLaunchKernelGGL(k_sentinel, dim3((out_size + 255) / 256), dim3(256), 0, stream,
                           (ushort_t*)d_out, out_size);
        return;
    }
    hipLaunchKernelGGL(k_transpose, dim3(64, 4, 4), dim3(256), 0, stream, d_in[0]);
    hipLaunchKernelGGL(k_proj, dim3(32, 6, 4), dim3(256), 0, stream,
                       d_in[1], d_in[2], d_in[3], d_in[4], d_in[5], d_in[6]);
    hipLaunchKernelGGL(k_attn, dim3(512), dim3(256), 0, stream);
    hipLaunchKernelGGL(k_combine, dim3(CHW / 2048, 4), dim3(256), 0, stream,
                       d_in[0], d_in[7], d_out);
}

// Round 7
// 239.347 us; speedup vs baseline: 1.0023x; 1.0023x over previous
//
#include <hip/hip_runtime.h>

typedef unsigned short ushort_t;
typedef unsigned int u32;
typedef _Float16 f16;
typedef f16 f16x8 __attribute__((ext_vector_type(8)));
typedef f16 f16x2 __attribute__((ext_vector_type(2)));
typedef ushort_t u16x8 __attribute__((ext_vector_type(8)));
typedef float f32x4 __attribute__((ext_vector_type(4)));
typedef float f32x16 __attribute__((ext_vector_type(16)));

#define C_DIM 256
#define HW 4096
#define CHW (C_DIM*HW)
#define L2E 1.4426950408889634f

// Device-global scratch. Internal pipeline f16.
__device__ __align__(16) f16 g_xbT[4 * CHW];
__device__ __align__(16) f16 g_q[4 * CHW];
__device__ __align__(16) f16 g_k[4 * CHW];
__device__ __align__(16) f16 g_v[4 * CHW];
__device__ __align__(16) f16 g_opart[16 * CHW];   // [slot=jq*4+n][c][i] normalized O^T
__device__ __align__(16) float g_ml[16 * 2 * HW]; // [slot][{m,l}][i]

__device__ __forceinline__ float bf2f(ushort_t h) {
    union { u32 u; float f; } v; v.u = ((u32)h) << 16; return v.f;
}
__device__ __forceinline__ ushort_t f2bf(float f) {
    union { float f; u32 u; } v; v.f = f;
    u32 r = v.u + 0x7FFF + ((v.u >> 16) & 1);
    return (ushort_t)(r >> 16);
}
__device__ __forceinline__ float fin0(float v) {
    return (v > -1e30f && v < 1e30f) ? v : 0.f;
}
__device__ __forceinline__ f16 sf16(float v) {
    return (f16)((v > -1e4f && v < 1e4f) ? v : 0.f);
}
__device__ __forceinline__ void gl2lds16(const f16* g, f16* l) {
    __builtin_amdgcn_global_load_lds(
        (const __attribute__((address_space(1))) u32*)g,
        (__attribute__((address_space(3))) u32*)l, 16, 0, 0);
}
// Local dtype probe: read 64 halves as bf16; f32-misread low-halves decode huge.
__device__ __forceinline__ int probe_mode(const void* p) {
    int lane = threadIdx.x & 63;
    float v = fabsf(bf2f(((const ushort_t*)p)[lane]));
    v = (v < 1e6f) ? v : 1e6f;
#pragma unroll
    for (int d = 1; d < 64; d <<= 1) v += __shfl_xor(v, d, 64);
    return (v * (1.f / 64.f) > 100.f) ? 1 : 0;
}

__global__ void k_sentinel(ushort_t* out, int n) {
    int i = blockIdx.x * 256 + threadIdx.x;
    if (i < n) out[i] = f2bf(777.f);
}

// ---------------- kernel 1: x (N,C,HW) -> g_xbT f16 (N,HW,C) ----------------
__global__ __launch_bounds__(256) void k_transpose(const void* __restrict__ xv) {
    __shared__ f16 t[64][66];
    int mode = probe_mode(xv);
    int n = blockIdx.z, c0 = blockIdx.y * 64, l0 = blockIdx.x * 64;
    int tid = threadIdx.x;
    f16* ob = g_xbT + n * CHW;
    int lq = (tid & 15) * 4;
    int cl = tid >> 4;
    if (mode == 0) {
        const ushort_t* xb = (const ushort_t*)xv + n * CHW;
#pragma unroll
        for (int p = 0; p < 4; ++p) {
            int c = cl + 16 * p;
            ushort4 v = *(const ushort4*)(xb + (c0 + c) * HW + l0 + lq);
            t[lq + 0][c] = sf16(bf2f(v.x));
            t[lq + 1][c] = sf16(bf2f(v.y));
            t[lq + 2][c] = sf16(bf2f(v.z));
            t[lq + 3][c] = sf16(bf2f(v.w));
        }
    } else {
        const float* xb = (const float*)xv + n * CHW;
#pragma unroll
        for (int p = 0; p < 4; ++p) {
            int c = cl + 16 * p;
            float4 v = *(const float4*)(xb + (c0 + c) * HW + l0 + lq);
            t[lq + 0][c] = sf16(v.x);
            t[lq + 1][c] = sf16(v.y);
            t[lq + 2][c] = sf16(v.z);
            t[lq + 3][c] = sf16(v.w);
        }
    }
    __syncthreads();
    int c2 = (tid & 31) * 2;
    int lr = tid >> 5;
#pragma unroll
    for (int p = 0; p < 8; ++p) {
        int l = lr + 8 * p;
        u32 pair = *(const u32*)&t[l][c2];
        *(u32*)(ob + (l0 + l) * C_DIM + c0 + c2) = pair;
    }
}

// ---------------- kernel 2: projections (f16 MFMA) ----------------
__global__ __launch_bounds__(256) void k_proj(
    const void* __restrict__ Wq, const void* __restrict__ bq,
    const void* __restrict__ Wk, const void* __restrict__ bk,
    const void* __restrict__ Wv, const void* __restrict__ bv)
{
    __shared__ __align__(16) f16 lds_x[128 * 64];
    __shared__ __align__(16) f16 lds_w[128 * 64];
    int l0 = blockIdx.x * 128;
    int og0 = blockIdx.y * 128;
    int n = blockIdx.z;
    int mat = og0 >> 8;       // 0=q,1=k,2=v
    int om0 = og0 & 255;
    const void* W = (mat == 0) ? Wq : (mat == 1) ? Wk : Wv;
    const void* bias = (mat == 0) ? bq : (mat == 1) ? bk : bv;
    int mode = probe_mode(W);
    int tid = threadIdx.x, w = tid >> 6, lane = tid & 63;
    int quad = lane >> 4, l16 = lane & 15;
    const f16* xb = g_xbT + n * CHW;

    f32x4 acc[2][8];
#pragma unroll
    for (int a = 0; a < 2; a++)
#pragma unroll
        for (int b = 0; b < 8; b++) acc[a][b] = f32x4{0.f, 0.f, 0.f, 0.f};

    for (int ch = 0; ch < 4; ++ch) {
        int cc0 = ch * 64;
        f16x8 xs[4], wsr[4];
#pragma unroll
        for (int ti = 0; ti < 4; ++ti) {
            int s = (w * 4 + ti) * 64 + lane;
            int row = s >> 3, gp = s & 7;
            xs[ti] = *(const f16x8*)(xb + (l0 + row) * C_DIM + cc0 + gp * 8);
            f16x8 h;
            if (mode == 0) {
                u16x8 wv = *(const u16x8*)((const ushort_t*)W + (om0 + row) * C_DIM + cc0 + gp * 8);
#pragma unroll
                for (int e = 0; e < 8; e++) h[e] = sf16(bf2f(wv[e]));
            } else {
                const float* wf = (const float*)W + (om0 + row) * C_DIM + cc0 + gp * 8;
#pragma unroll
                for (int e = 0; e < 8; e++) h[e] = sf16(wf[e]);
            }
            wsr[ti] = h;
        }
        __syncthreads();
#pragma unroll
        for (int ti = 0; ti < 4; ++ti) {
            int s = (w * 4 + ti) * 64 + lane;
            int row = s >> 3, gp = s & 7;
            int pos = gp ^ (row & 7);
            *(f16x8*)(lds_x + (row * 8 + pos) * 8) = xs[ti];
            *(f16x8*)(lds_w + (row * 8 + pos) * 8) = wsr[ti];
        }
        __syncthreads();
#pragma unroll
        for (int ks = 0; ks < 2; ++ks) {
            f16x8 af[2];
#pragma unroll
            for (int mt = 0; mt < 2; ++mt) {
                int row = w * 32 + mt * 16 + l16;
                int g = ks * 4 + quad;
                int pos = g ^ (row & 7);
                af[mt] = *(const f16x8*)(lds_x + (row * 8 + pos) * 8);
            }
#pragma unroll
            for (int nt = 0; nt < 8; ++nt) {
                int rowo = nt * 16 + l16;
                int g = ks * 4 + quad;
                int pos = g ^ (rowo & 7);
                f16x8 bfv = *(const f16x8*)(lds_w + (rowo * 8 + pos) * 8);
                if (mat < 2) {
                    acc[0][nt] = __builtin_amdgcn_mfma_f32_16x16x32_f16(af[0], bfv, acc[0][nt], 0, 0, 0);
                    acc[1][nt] = __builtin_amdgcn_mfma_f32_16x16x32_f16(af[1], bfv, acc[1][nt], 0, 0, 0);
                } else {
                    acc[0][nt] = __builtin_amdgcn_mfma_f32_16x16x32_f16(bfv, af[0], acc[0][nt], 0, 0, 0);
                    acc[1][nt] = __builtin_amdgcn_mfma_f32_16x16x32_f16(bfv, af[1], acc[1][nt], 0, 0, 0);
                }
            }
        }
        __syncthreads();
    }

    auto loadb = [&](int i) -> float {
        return mode ? ((const float*)bias)[i] : bf2f(((const ushort_t*)bias)[i]);
    };
    if (mat < 2) {
        f16* T = ((mat == 0) ? g_q : g_k) + n * CHW;
        float bvv[8];
#pragma unroll
        for (int nt = 0; nt < 8; nt++) bvv[nt] = loadb(om0 + nt * 16 + l16);
#pragma unroll
        for (int mt = 0; mt < 2; mt++)
#pragma unroll
            for (int nt = 0; nt < 8; nt++)
#pragma unroll
                for (int r = 0; r < 4; r++) {
                    int l = l0 + w * 32 + mt * 16 + quad * 4 + r;
                    int o = om0 + nt * 16 + l16;
                    T[l * C_DIM + o] = sf16(acc[mt][nt][r] + bvv[nt]);
                }
    } else {
        f16* T = g_v + n * CHW;
#pragma unroll
        for (int mt = 0; mt < 2; mt++)
#pragma unroll
            for (int nt = 0; nt < 8; nt++)
#pragma unroll
                for (int r = 0; r < 4; r++) {
                    int o = om0 + nt * 16 + quad * 4 + r;
                    int l = l0 + w * 32 + mt * 16 + l16;
                    T[o * HW + l] = sf16(acc[mt][nt][r] + loadb(o));
                }
    }
}

// ---------------- kernel 3: flash attention, 32x32x16 MFMA ----------------
// Per wave: one 32x32 S^T tile (A=K,B=Q so row j is in-lane), in-register
// softmax + P^T fragment build (cvt + shfl_xor(32), no LDS round-trip).
// This round: (a) S accumulation split into 2 alternating chains, (b) PV(it-1)
// MFMAs manually interleaved 1:1 between S(it) MFMAs so dependent-MFMA latency
// is hidden by independent issue, (c) l_ kept as per-half partial (cross-half
// shfl deferred to epilogue), (d) V double-buffered staging V(it) at iter it.
// LDS 64KB -> 2 blocks/CU. All ds_read_b128 contiguous 512B/half -> 0 conflicts.
__device__ __forceinline__ f16x8 pack_pfrag(const float* p, int h) {
    // p[r] holds P^T[j = (r&3)+8*(r>>2)+4*h][i = lane&31] for one 16-j chunk.
    // Build B-operand frag: lane needs j = h*8+e (e=0..7) of this chunk.
    union PK { u32 u; f16x2 h2; } t0, t1, t2, t3;
    t0.h2 = f16x2{(f16)p[0], (f16)p[1]};
    t1.h2 = f16x2{(f16)p[2], (f16)p[3]};
    t2.h2 = f16x2{(f16)p[4], (f16)p[5]};
    t3.h2 = f16x2{(f16)p[6], (f16)p[7]};
    u32 sa = __shfl_xor(t0.u, 32, 64);
    u32 sb = __shfl_xor(t1.u, 32, 64);
    u32 sc = __shfl_xor(t2.u, 32, 64);
    u32 sd = __shfl_xor(t3.u, 32, 64);
    union RW { u32 w[4]; f16x8 v; } r;
    r.w[0] = h ? sc : t0.u;   // k{0,1}: h0 j{0,1}=own t0 ; h1 j{8,9}=partner t2
    r.w[1] = h ? sd : t1.u;   // k{2,3}
    r.w[2] = h ? t2.u : sa;   // k{4,5}: h0 j{4,5}=partner t0 ; h1 j{12,13}=own t2
    r.w[3] = h ? t3.u : sb;   // k{6,7}
    return r.v;
}

__global__ __launch_bounds__(256, 2) void k_attn() {
    __shared__ __align__(16) f16 smem[32768];   // 64 KB
    f16* kbuf = smem;            // 2 slots x 8192 halves, granule g=cg*32+j: K[j][cg*8..+8]
    f16* vbuf = smem + 16384;    // 2 slots x 8192 halves, granule g=jg*256+c: V[c][jg*8..+8]

    int bid = blockIdx.x;
    int x8 = bid & 7;
    int n = x8 >> 1, jhi = x8 & 1;
    int rest = bid >> 3;
    int jlo = rest & 1;
    int i0 = (rest >> 1) * 128;
    int jq = jhi * 2 + jlo;
    int tid = threadIdx.x, w = tid >> 6, lane = tid & 63;
    int j5 = lane & 31, h = lane >> 5;

    const f16* Qb = g_q + n * CHW;
    const f16* Kb = g_k + n * CHW;
    const f16* Vb = g_v + n * CHW;

    // ---- Q fragments in registers (B operand: n=i=lane&31, k=h*8+e) ----
    f16x8 qf[16];
    {
        const f16* qrow = Qb + (i0 + w * 32 + j5) * C_DIM + h * 8;
#pragma unroll
        for (int ck = 0; ck < 16; ++ck)
            qf[ck] = *(const f16x8*)(qrow + ck * 16);
    }

    // per-lane LDS read offsets (halves)
    int k_lane = h * 256 + j5 * 8;    // + ck*512          (cg = ck*2 + h, j = j5)
    int v_lane = h * 2048 + j5 * 8;   // + js*4096 + ct*256 (jg = js*2 + h, c = ct*32+j5)

    // staging source pointers (per-lane), advance per iter
    const f16* ksrc = Kb + (jq * 1024 + j5) * C_DIM + (w * 2 + h) * 8;
    const f16* vsrc = Vb + tid * HW + jq * 1024;
    int dst_w = w * 512;              // wave-uniform LDS dest offset (halves)

    f32x16 o_acc[8];
#pragma unroll
    for (int ct = 0; ct < 8; ++ct)
#pragma unroll
        for (int r = 0; r < 16; ++r) o_acc[ct][r] = 0.f;

    float m_ = -1e30f, l_ = 0.f, al_prev = 1.f;
    f16x8 pf0 = {}, pf1 = {};

    // prologue: stage K(0) -> kslot0  (V(0) is staged during iter 0)
#pragma unroll
    for (int s = 0; s < 4; ++s) gl2lds16(ksrc + s * 64, kbuf + s * 2048 + dst_w);
    ksrc += 32 * C_DIM;
    __syncthreads();

    for (int it = 0; it < 32; ++it) {
        int kcur = it & 1;
        // stage K(it+1) and V(it); both drained at this iter's end barrier
        if (it < 31) {
#pragma unroll
            for (int s = 0; s < 4; ++s)
                gl2lds16(ksrc + s * 64, kbuf + (kcur ^ 1) * 8192 + s * 2048 + dst_w);
            ksrc += 32 * C_DIM;
        }
#pragma unroll
        for (int s = 0; s < 4; ++s)
            gl2lds16(vsrc + s * 8, vbuf + (it & 1) * 8192 + s * 2048 + dst_w);
        vsrc += 32;

        // ---- rescale O (rare: quantized max) before deferred PV ----
        if (it > 0 && __any(al_prev < 1.f)) {
#pragma unroll
            for (int ct = 0; ct < 8; ++ct)
#pragma unroll
                for (int r = 0; r < 16; ++r) o_acc[ct][r] *= al_prev;
        }

        // ---- S^T(it) = K Q^T (2 alternating acc chains) interleaved with
        //      PV(it-1): O^T += V(it-1) P^T(it-1)  (independent MFMAs) ----
        const f16* kb = kbuf + kcur * 8192 + k_lane;
        f32x16 sa, sb;
#pragma unroll
        for (int r = 0; r < 16; ++r) { sa[r] = 0.f; sb[r] = 0.f; }
        __builtin_amdgcn_s_setprio(1);
        if (it > 0) {
            const f16* vb = vbuf + ((it - 1) & 1) * 8192 + v_lane;
#pragma unroll
            for (int ck = 0; ck < 16; ++ck) {
                f16x8 kf = *(const f16x8*)(kb + ck * 512);
                if (ck & 1) sb = __builtin_amdgcn_mfma_f32_32x32x16_f16(kf, qf[ck], sb, 0, 0, 0);
                else        sa = __builtin_amdgcn_mfma_f32_32x32x16_f16(kf, qf[ck], sa, 0, 0, 0);
                f16x8 vf = *(const f16x8*)(vb + (ck & 1) * 4096 + (ck >> 1) * 256);
                o_acc[ck >> 1] = __builtin_amdgcn_mfma_f32_32x32x16_f16(
                    vf, (ck & 1) ? pf1 : pf0, o_acc[ck >> 1], 0, 0, 0);
            }
        } else {
#pragma unroll
            for (int ck = 0; ck < 16; ++ck) {
                f16x8 kf = *(const f16x8*)(kb + ck * 512);
                if (ck & 1) sb = __builtin_amdgcn_mfma_f32_32x32x16_f16(kf, qf[ck], sb, 0, 0, 0);
                else        sa = __builtin_amdgcn_mfma_f32_32x32x16_f16(kf, qf[ck], sa, 0, 0, 0);
            }
        }
        __builtin_amdgcn_s_setprio(0);
        f32x16 st;
#pragma unroll
        for (int r = 0; r < 16; ++r) st[r] = sa[r] + sb[r];

        // ---- online softmax over j (rows of S^T), per i = lane&31 ----
        float mx0 = fmaxf(fmaxf(st[0], st[1]), fmaxf(st[2], st[3]));
        float mx1 = fmaxf(fmaxf(st[4], st[5]), fmaxf(st[6], st[7]));
        float mx2 = fmaxf(fmaxf(st[8], st[9]), fmaxf(st[10], st[11]));
        float mx3 = fmaxf(fmaxf(st[12], st[13]), fmaxf(st[14], st[15]));
        float smax = fmaxf(fmaxf(mx0, mx1), fmaxf(mx2, mx3));
        smax = fmaxf(smax, __shfl_xor(smax, 32, 64));
        float mq = __builtin_ceilf(smax * 0.125f) * 8.f;   // quantized max
        float mn = fmaxf(m_, mq);
        float al = __builtin_amdgcn_exp2f((m_ - mn) * L2E);
        float nl = -mn * L2E;
        float p[16];
#pragma unroll
        for (int r = 0; r < 16; ++r)
            p[r] = __builtin_amdgcn_exp2f(st[r] * L2E + nl);
        float a0 = (p[0] + p[1]) + (p[2] + p[3]);
        float a1 = (p[4] + p[5]) + (p[6] + p[7]);
        float a2 = (p[8] + p[9]) + (p[10] + p[11]);
        float a3 = (p[12] + p[13]) + (p[14] + p[15]);
        float rs = (a0 + a1) + (a2 + a3);   // per-half partial; cross-add deferred
        m_ = mn;
        l_ = l_ * al + rs;
        al_prev = al;
        pf0 = pack_pfrag(p, h);
        pf1 = pack_pfrag(p + 8, h);

        __syncthreads();   // staged K(it+1),V(it) drained; buffer reads of (it) done
    }

    // ---- final PV(31): V(31) staged at it=31, slot 1 ----
    {
        if (__any(al_prev < 1.f)) {
#pragma unroll
            for (int ct = 0; ct < 8; ++ct)
#pragma unroll
                for (int r = 0; r < 16; ++r) o_acc[ct][r] *= al_prev;
        }
        const f16* vb = vbuf + 8192 + v_lane;
#pragma unroll
        for (int ct = 0; ct < 8; ++ct) {
            f16x8 v0 = *(const f16x8*)(vb + ct * 256);
            f16x8 v1 = *(const f16x8*)(vb + 4096 + ct * 256);
            o_acc[ct] = __builtin_amdgcn_mfma_f32_32x32x16_f16(v0, pf0, o_acc[ct], 0, 0, 0);
            o_acc[ct] = __builtin_amdgcn_mfma_f32_32x32x16_f16(v1, pf1, o_acc[ct], 0, 0, 0);
        }
    }

    // ---- epilogue: complete the deferred cross-half l reduction ----
    l_ += __shfl_xor(l_, 32, 64);

    // ---- write partials ----
    int slot = jq * 4 + n;
    int i_out = i0 + w * 32 + j5;
    if (h == 0) {
        g_ml[(slot * 2 + 0) * HW + i_out] = m_;
        g_ml[(slot * 2 + 1) * HW + i_out] = l_;
    }
    float inv = (l_ > 1e-30f) ? 1.f / l_ : 0.f;
    f16* ob = g_opart + slot * CHW + i_out;
#pragma unroll
    for (int ct = 0; ct < 8; ++ct) {
        int cbase = ct * 32 + 4 * h;
#pragma unroll
        for (int r = 0; r < 16; ++r) {
            int c = cbase + (r & 3) + 8 * (r >> 2);
            ob[c * HW] = (f16)(o_acc[ct][r] * inv);
        }
    }
}

// ---------------- kernel 4: merge 4 j-quarters + residual + store (8-wide) ----------------
__global__ __launch_bounds__(256) void k_combine(
    const void* __restrict__ xv, const void* __restrict__ gv, void* __restrict__ outv)
{
    int mode = probe_mode(xv);
    float gam = fin0(mode ? ((const float*)gv)[0] : bf2f(((const ushort_t*)gv)[0]));
    int n = blockIdx.y;
    int off = blockIdx.x * 2048 + threadIdx.x * 8;   // 8 consecutive i, same c
    int i = off & (HW - 1);

    u16x8 op[4];
    float ms[4][8], ls[4][8];
#pragma unroll
    for (int s = 0; s < 4; ++s) {
        int slot = s * 4 + n;
        op[s] = *(const u16x8*)((const ushort_t*)g_opart + slot * CHW + off);
        float4 mA = *(const float4*)&g_ml[(slot * 2 + 0) * HW + i];
        float4 mB = *(const float4*)&g_ml[(slot * 2 + 0) * HW + i + 4];
        float4 lA = *(const float4*)&g_ml[(slot * 2 + 1) * HW + i];
        float4 lB = *(const float4*)&g_ml[(slot * 2 + 1) * HW + i + 4];
        ms[s][0]=mA.x; ms[s][1]=mA.y; ms[s][2]=mA.z; ms[s][3]=mA.w;
        ms[s][4]=mB.x; ms[s][5]=mB.y; ms[s][6]=mB.z; ms[s][7]=mB.w;
        ls[s][0]=lA.x; ls[s][1]=lA.y; ls[s][2]=lA.z; ls[s][3]=lA.w;
        ls[s][4]=lB.x; ls[s][5]=lB.y; ls[s][6]=lB.z; ls[s][7]=lB.w;
    }

    float o[8];
#pragma unroll
    for (int e = 0; e < 8; ++e) {
        float m = fmaxf(fmaxf(ms[0][e], ms[1][e]), fmaxf(ms[2][e], ms[3][e]));
        float num = 0.f, den = 0.f;
#pragma unroll
        for (int s = 0; s < 4; ++s) {
            float wgt = __builtin_amdgcn_exp2f((ms[s][e] - m) * L2E) * ls[s][e];
            union { ushort_t u; f16 h; } cv; cv.u = (ushort_t)op[s][e];
            num += wgt * (float)cv.h;
            den += wgt;
        }
        o[e] = (den > 1e-30f) ? num / den : 0.f;
    }

    if (mode == 0) {
        u16x8 xp = *(const u16x8*)((const ushort_t*)xv + n * CHW + off);
        u16x8 res;
#pragma unroll
        for (int e = 0; e < 8; ++e)
            res[e] = f2bf(fin0(bf2f((ushort_t)xp[e]) + gam * o[e]));
        *(u16x8*)((ushort_t*)outv + n * CHW + off) = res;
    } else {
        const float* xb = (const float*)xv + n * CHW + off;
        float* outb = (float*)outv + n * CHW + off;
        float4 xA = *(const float4*)xb;
        float4 xB = *(const float4*)(xb + 4);
        float4 rA, rB;
        rA.x = fin0(xA.x + gam * o[0]); rA.y = fin0(xA.y + gam * o[1]);
        rA.z = fin0(xA.z + gam * o[2]); rA.w = fin0(xA.w + gam * o[3]);
        rB.x = fin0(xB.x + gam * o[4]); rB.y = fin0(xB.y + gam * o[5]);
        rB.z = fin0(xB.z + gam * o[6]); rB.w = fin0(xB.w + gam * o[7]);
        *(float4*)outb = rA;
        *(float4*)(outb + 4) = rB;
    }
}

extern "C" void kernel_launch(void* const* d_in, const int* in_sizes, int n_in,
                              void* d_out, int out_size, void* d_ws, size_t ws_size,
                              hipStream_t stream) {
    (void)d_ws; (void)ws_size;
    bool ok = (n_in == 8) &&
              in_sizes[0] == 4 * CHW &&
              in_sizes[1] == C_DIM * C_DIM && in_sizes[2] == C_DIM &&
              in_sizes[3] == C_DIM * C_DIM && in_sizes[4] == C_DIM &&
              in_sizes[5] == C_DIM * C_DIM && in_sizes[6] == C_DIM &&
              in_sizes[7] == 1 && out_size == 4 * CHW;
    if (!ok) {
        hipLaunchKernelGGL(k_sentinel, dim3((out_size + 255) / 256), dim3(256), 0, stream,
                           (ushort_t*)d_out, out_size);
        return;
    }
    hipLaunchKernelGGL(k_transpose, dim3(64, 4, 4), dim3(256), 0, stream, d_in[0]);
    hipLaunchKernelGGL(k_proj, dim3(32, 6, 4), dim3(256), 0, stream,
                       d_in[1], d_in[2], d_in[3], d_in[4], d_in[5], d_in[6]);
    hipLaunchKernelGGL(k_attn, dim3(512), dim3(256), 0, stream);
    hipLaunchKernelGGL(k_combine, dim3(CHW / 2048, 4), dim3(256), 0, stream,
                       d_in[0], d_in[7], d_out);
}